// Round 2
// baseline (5997.052 us; speedup 1.0000x reference)
//
#include <hip/hip_runtime.h>
#include <hip/hip_bf16.h>
#include <cstdint>
#include <cstddef>

// ---------------------------------------------------------------------------
// Model dims: NL=32, D=256, DI=512, N=16, R=16, K=4, V=4096, FF=1024, B=32, L=256
// ALL harness inputs are float32; output is float32 (threshold analysis R1).
// GEMMs run bf16 MFMA (weights converted in-ws); residual + dt/B/C stay f32.
// ---------------------------------------------------------------------------

typedef __bf16 v8bf __attribute__((ext_vector_type(8)));
typedef float  v4f  __attribute__((ext_vector_type(4)));

__device__ __forceinline__ void async_copy16(const void* g, void* l) {
  __builtin_amdgcn_global_load_lds((const __attribute__((address_space(1))) void*)g,
                                   (__attribute__((address_space(3))) void*)l, 16, 0, 0);
}

__device__ __forceinline__ float bf(__bf16 v) { return (float)v; }

// ---------------- f32 -> bf16 convert ------------------------------------
__global__ __launch_bounds__(256) void f2b_k(const float* __restrict__ X,
                                             __bf16* __restrict__ O) {
  size_t i = (size_t)blockIdx.x * 256 + threadIdx.x;
  O[i] = (__bf16)X[i];
}

// ---------------- embedding gather: X(f32) = emb[token] -------------------
__global__ __launch_bounds__(256) void embed_k(const int* __restrict__ tok,
                                               const float* __restrict__ emb,
                                               float* __restrict__ X) {
  int row = blockIdx.x;            // 8192 tokens
  int t   = threadIdx.x;           // D=256
  X[(size_t)row * 256 + t] = emb[(size_t)tok[row] * 256 + t];
}

// ---------------- layernorm over D=256, one block per token ----------------
__global__ __launch_bounds__(256) void ln_k(const float* __restrict__ X,
                                            const float* __restrict__ w,
                                            const float* __restrict__ b,
                                            __bf16* __restrict__ H) {
  int row = blockIdx.x;
  int t   = threadIdx.x;
  float v = X[(size_t)row * 256 + t];
  float s = v, q = v * v;
  #pragma unroll
  for (int o = 32; o > 0; o >>= 1) { s += __shfl_xor(s, o); q += __shfl_xor(q, o); }
  __shared__ float ss[4], qq[4];
  int wv = t >> 6;
  if ((t & 63) == 0) { ss[wv] = s; qq[wv] = q; }
  __syncthreads();
  s = ss[0] + ss[1] + ss[2] + ss[3];
  q = qq[0] + qq[1] + qq[2] + qq[3];
  float mu  = s * (1.f / 256.f);
  float var = q * (1.f / 256.f) - mu * mu;
  float r   = rsqrtf(var + 1e-5f);
  H[(size_t)row * 256 + t] = (__bf16)((v - mu) * r * w[t] + b[t]);
}

// ---------------- causal depthwise conv (K=4) + SiLU ----------------------
// XZ: (8192, 1024) bf16, xm = XZ[:, 0:512].  XC: (8192, 512) bf16
__global__ __launch_bounds__(256) void conv_silu_k(const __bf16* __restrict__ XZ,
                                                   const float* __restrict__ cw,
                                                   const float* __restrict__ cb,
                                                   __bf16* __restrict__ XC) {
  int idx = blockIdx.x * 256 + threadIdx.x;   // (bl, e), e fastest
  int e   = idx & 511;
  int bl  = idx >> 9;
  int l   = bl & 255;                         // position within sequence
  float acc = cb[e];
  #pragma unroll
  for (int k = 0; k < 4; ++k) {
    int ls = l + k - 3;
    if (ls >= 0)
      acc += bf(XZ[(size_t)(bl + k - 3) * 1024 + e]) * cw[e * 4 + k];
  }
  float sg = 1.f / (1.f + __expf(-acc));
  XC[idx] = (__bf16)(acc * sg);
}

// ---------------- generic MFMA bf16 GEMM: C(M,N) = A(M,K) @ W(N,K)^T -------
// BM=BN=128, BK=32, 256 threads (4 waves 2x2, each 64x64 = 4x4 of 16x16).
// EPI: 0 = store bf16; 1 = +bias(f32), relu, bf16; 2 = +bias(f32), f32 out;
//      3 = resid f32 in-place; 4 = store f32
template <int EPI>
__global__ __launch_bounds__(256, 2)
void gemm_bt(const __bf16* __restrict__ A, const __bf16* __restrict__ W,
             void* outp, const float* __restrict__ bias, const float* resid,
             int M, int N, int K) {
  __shared__ __align__(16) __bf16 sA[128 * 32];
  __shared__ __align__(16) __bf16 sB[128 * 32];
  const int tid  = threadIdx.x;
  const int bm0  = blockIdx.y << 7;
  const int bn0  = blockIdx.x << 7;
  const int lane = tid & 63;
  const int wv   = tid >> 6;
  const int wm   = (wv >> 1) << 6;
  const int wn   = (wv & 1) << 6;
  const int lr   = lane & 15;
  const int lk   = lane >> 4;

  v4f acc[4][4] = {};

  const int r0 = tid >> 2;
  const int c0 = (tid & 3) << 3;
  const int wbase = (tid & ~63) << 3;   // wave-uniform LDS element base

  int rA0 = bm0 + r0, rA1 = bm0 + 64 + r0;
  int rB0 = bn0 + r0;      if (rB0 >= N) rB0 = N - 1;   // clamp (N=48 case)
  int rB1 = bn0 + 64 + r0; if (rB1 >= N) rB1 = N - 1;

  const __bf16* gA0 = A + (size_t)rA0 * K + c0;
  const __bf16* gA1 = A + (size_t)rA1 * K + c0;
  const __bf16* gB0 = W + (size_t)rB0 * K + c0;
  const __bf16* gB1 = W + (size_t)rB1 * K + c0;

  for (int kk = 0; kk < K; kk += 32) {
    async_copy16(gA0 + kk, sA + wbase);
    async_copy16(gA1 + kk, sA + 2048 + wbase);
    async_copy16(gB0 + kk, sB + wbase);
    async_copy16(gB1 + kk, sB + 2048 + wbase);
    __syncthreads();
    v8bf af[4], bfr[4];
    #pragma unroll
    for (int i = 0; i < 4; ++i)
      af[i] = *(const v8bf*)(sA + ((wm + i * 16 + lr) << 5) + (lk << 3));
    #pragma unroll
    for (int j = 0; j < 4; ++j)
      bfr[j] = *(const v8bf*)(sB + ((wn + j * 16 + lr) << 5) + (lk << 3));
    #pragma unroll
    for (int i = 0; i < 4; ++i)
      #pragma unroll
      for (int j = 0; j < 4; ++j)
        acc[i][j] = __builtin_amdgcn_mfma_f32_16x16x32_bf16(af[i], bfr[j], acc[i][j], 0, 0, 0);
    __syncthreads();
  }

  // C/D layout: col = lane&15, row = (lane>>4)*4 + reg   [measured m89]
  #pragma unroll
  for (int i = 0; i < 4; ++i) {
    #pragma unroll
    for (int j = 0; j < 4; ++j) {
      int gc = bn0 + wn + j * 16 + lr;
      if (gc < N) {
        #pragma unroll
        for (int v = 0; v < 4; ++v) {
          int gr = bm0 + wm + i * 16 + (lk << 2) + v;
          float val = acc[i][j][v];
          size_t idx = (size_t)gr * N + gc;
          if (EPI == 0) {
            ((__bf16*)outp)[idx] = (__bf16)val;
          } else if (EPI == 1) {
            val += bias[gc]; val = fmaxf(val, 0.f);
            ((__bf16*)outp)[idx] = (__bf16)val;
          } else if (EPI == 2) {
            ((float*)outp)[idx] = val + bias[gc];
          } else if (EPI == 3) {
            float r = resid[idx];
            ((float*)outp)[idx] = r + val;
          } else {
            ((float*)outp)[idx] = val;
          }
        }
      }
    }
  }
}

// ---------------- SSM scan, chunked (C=8 chunks of Lc=32) ------------------
// dt recomputed in-pass from DBC[:,0:16] @ dtw^T + dtb (softplus).
// DBC row (f32): [dt_raw(16) | B(16) | C(16)], 192 B, 16B-aligned.
__global__ __launch_bounds__(256, 2)
void scan_pass1(const float* __restrict__ DBC, const __bf16* __restrict__ XC,
                const float* __restrict__ dtw, const float* __restrict__ dtb,
                const float* __restrict__ Alog,
                float* __restrict__ PART, float* __restrict__ PROD) {
  const int e = blockIdx.x * 256 + threadIdx.x;   // 0..511
  const int b = blockIdx.y;                       // 0..31
  const int c = blockIdx.z;                       // 0..7
  float Arow[16], Wdt[16];
  #pragma unroll
  for (int n = 0; n < 16; ++n) {
    Arow[n] = -__expf(Alog[e * 16 + n]);
    Wdt[n]  = dtw[e * 16 + n];
  }
  const float bias = dtb[e];
  float part[16], prod[16];
  #pragma unroll
  for (int n = 0; n < 16; ++n) { part[n] = 0.f; prod[n] = 1.f; }
  const int bl0 = b * 256 + c * 32;
  for (int tt = 0; tt < 32; ++tt) {
    const v4f* dp = (const v4f*)(DBC + (size_t)(bl0 + tt) * 48);
    v4f d0 = dp[0], d1 = dp[1], d2 = dp[2], d3 = dp[3];
    v4f bv0 = dp[4], bv1 = dp[5], bv2 = dp[6], bv3 = dp[7];
    float dtv = bias;
    #pragma unroll
    for (int r = 0; r < 4; ++r)
      dtv += d0[r] * Wdt[r] + d1[r] * Wdt[r + 4] + d2[r] * Wdt[r + 8] + d3[r] * Wdt[r + 12];
    dtv = (dtv > 20.f) ? dtv : log1pf(__expf(dtv));          // softplus
    float x = bf(XC[(size_t)(bl0 + tt) * 512 + e]);
    float dtx = dtv * x;
    float Bv[16];
    #pragma unroll
    for (int r = 0; r < 4; ++r) { Bv[r] = bv0[r]; Bv[r+4] = bv1[r]; Bv[r+8] = bv2[r]; Bv[r+12] = bv3[r]; }
    #pragma unroll
    for (int n = 0; n < 16; ++n) {
      float dA = __expf(dtv * Arow[n]);
      part[n] = part[n] * dA + dtx * Bv[n];
      prod[n] *= dA;
    }
  }
  size_t o = (((size_t)c * 32 + b) * 512 + e) * 16;
  #pragma unroll
  for (int n = 0; n < 16; ++n) { PART[o + n] = part[n]; PROD[o + n] = prod[n]; }
}

// serial combine across 8 chunks: h0[c] = state entering chunk c
__global__ __launch_bounds__(256) void scan_combine(const float* __restrict__ PART,
                                                    const float* __restrict__ PROD,
                                                    float* __restrict__ H0) {
  size_t idx = (size_t)blockIdx.x * 256 + threadIdx.x;   // (b*512+e)*16+n, 262144 total
  float h = 0.f;
  #pragma unroll
  for (int c = 0; c < 8; ++c) {
    size_t o = (size_t)c * 262144 + idx;
    H0[o] = h;
    h = PROD[o] * h + PART[o];
  }
}

// pass2: replay with correct h0; fused y = (y_ssm + xc*Dskip) * silu(z)
__global__ __launch_bounds__(256, 2)
void scan_pass2(const float* __restrict__ DBC, const __bf16* __restrict__ XC,
                const __bf16* __restrict__ XZ,
                const float* __restrict__ dtw, const float* __restrict__ dtb,
                const float* __restrict__ Alog, const float* __restrict__ Dskip,
                const float* __restrict__ H0, __bf16* __restrict__ Y) {
  const int e = blockIdx.x * 256 + threadIdx.x;
  const int b = blockIdx.y;
  const int c = blockIdx.z;
  float Arow[16], Wdt[16];
  #pragma unroll
  for (int n = 0; n < 16; ++n) {
    Arow[n] = -__expf(Alog[e * 16 + n]);
    Wdt[n]  = dtw[e * 16 + n];
  }
  const float bias = dtb[e];
  const float Dsk  = Dskip[e];
  float h[16];
  {
    size_t o = (((size_t)c * 32 + b) * 512 + e) * 16;
    #pragma unroll
    for (int n = 0; n < 16; ++n) h[n] = H0[o + n];
  }
  const int bl0 = b * 256 + c * 32;
  for (int tt = 0; tt < 32; ++tt) {
    const v4f* dp = (const v4f*)(DBC + (size_t)(bl0 + tt) * 48);
    v4f d0 = dp[0], d1 = dp[1], d2 = dp[2], d3 = dp[3];
    v4f bv0 = dp[4], bv1 = dp[5], bv2 = dp[6], bv3 = dp[7];
    v4f cv0 = dp[8], cv1 = dp[9], cv2 = dp[10], cv3 = dp[11];
    float dtv = bias;
    #pragma unroll
    for (int r = 0; r < 4; ++r)
      dtv += d0[r] * Wdt[r] + d1[r] * Wdt[r + 4] + d2[r] * Wdt[r + 8] + d3[r] * Wdt[r + 12];
    dtv = (dtv > 20.f) ? dtv : log1pf(__expf(dtv));
    float x = bf(XC[(size_t)(bl0 + tt) * 512 + e]);
    float dtx = dtv * x;
    float Bv[16], Cv[16];
    #pragma unroll
    for (int r = 0; r < 4; ++r) {
      Bv[r] = bv0[r]; Bv[r+4] = bv1[r]; Bv[r+8] = bv2[r]; Bv[r+12] = bv3[r];
      Cv[r] = cv0[r]; Cv[r+4] = cv1[r]; Cv[r+8] = cv2[r]; Cv[r+12] = cv3[r];
    }
    float y = 0.f;
    #pragma unroll
    for (int n = 0; n < 16; ++n) {
      float dA = __expf(dtv * Arow[n]);
      h[n] = h[n] * dA + dtx * Bv[n];
      y += h[n] * Cv[n];
    }
    float z  = bf(XZ[(size_t)(bl0 + tt) * 1024 + 512 + e]);
    float sg = z / (1.f + __expf(-z));                        // silu(z)
    Y[(size_t)(bl0 + tt) * 512 + e] = (__bf16)((y + x * Dsk) * sg);
  }
}

// ---------------------------------------------------------------------------
// Workspace layout (bytes). Total ~103.5 MB.
// ---------------------------------------------------------------------------
constexpr size_t OFF_WIN  = 0;          // bf16 32*1024*256  in_proj
constexpr size_t OFF_WXP  = 16777216;   // bf16 32*48*512    x_proj
constexpr size_t OFF_WOUT = 18350080;   // bf16 32*256*512   out_proj
constexpr size_t OFF_WW1  = 26738688;   // bf16 1024*256
constexpr size_t OFF_WW2  = 27262976;   // bf16 4096*1024
constexpr size_t OFF_X    = 35651584;   // f32  8192*256   (residual stream)
constexpr size_t OFF_H    = 44040192;   // bf16 8192*256   (LN output)
constexpr size_t OFF_XZ   = 48234496;   // bf16 8192*1024  (in_proj out)
constexpr size_t OFF_XC   = 65011712;   // bf16 8192*512   (conv+silu out)
constexpr size_t OFF_DBC  = 73400320;   // f32  8192*48    (x_proj out)
constexpr size_t OFF_Y    = 74973184;   // bf16 8192*512   (gated ssm out)
constexpr size_t OFF_PART = 83361792;   // f32  8*32*512*16  (alias: XB head in)
constexpr size_t OFF_PROD = 91750400;   // f32  same         (alias: HH head mid, 16MB spans PROD+H0)
constexpr size_t OFF_H0   = 100139008;  // f32  same

extern "C" void kernel_launch(void* const* d_in, const int* in_sizes, int n_in,
                              void* d_out, int out_size, void* d_ws, size_t ws_size,
                              hipStream_t stream) {
  const int*   tok  = (const int*)d_in[0];
  const float* emb  = (const float*)d_in[1];
  const float* lnw  = (const float*)d_in[2];
  const float* lnb  = (const float*)d_in[3];
  const float* inw  = (const float*)d_in[4];
  const float* cw   = (const float*)d_in[5];
  const float* cb   = (const float*)d_in[6];
  const float* xpw  = (const float*)d_in[7];
  const float* dtw  = (const float*)d_in[8];
  const float* dtb  = (const float*)d_in[9];
  const float* alog = (const float*)d_in[10];
  const float* dsk  = (const float*)d_in[11];
  const float* outw = (const float*)d_in[12];
  const float* W1   = (const float*)d_in[13];
  const float* b1   = (const float*)d_in[14];
  const float* W2   = (const float*)d_in[15];
  const float* b2   = (const float*)d_in[16];

  char* ws = (char*)d_ws;
  __bf16* WIN  = (__bf16*)(ws + OFF_WIN);
  __bf16* WXP  = (__bf16*)(ws + OFF_WXP);
  __bf16* WOUT = (__bf16*)(ws + OFF_WOUT);
  __bf16* WW1  = (__bf16*)(ws + OFF_WW1);
  __bf16* WW2  = (__bf16*)(ws + OFF_WW2);
  float*  X    = (float*)(ws + OFF_X);
  __bf16* H    = (__bf16*)(ws + OFF_H);
  __bf16* XZ   = (__bf16*)(ws + OFF_XZ);
  __bf16* XC   = (__bf16*)(ws + OFF_XC);
  float*  DBC  = (float*)(ws + OFF_DBC);
  __bf16* Y    = (__bf16*)(ws + OFF_Y);
  float*  PART = (float*)(ws + OFF_PART);
  float*  PROD = (float*)(ws + OFF_PROD);
  float*  H0   = (float*)(ws + OFF_H0);
  __bf16* XB   = (__bf16*)(ws + OFF_PART);   // head-phase aliases (dead regions)
  __bf16* HH   = (__bf16*)(ws + OFF_PROD);

  // weight conversions (every call; ws is re-poisoned between calls)
  f2b_k<<<32768, 256, 0, stream>>>(inw,  WIN);    // 8,388,608
  f2b_k<<<3072,  256, 0, stream>>>(xpw,  WXP);    //   786,432
  f2b_k<<<16384, 256, 0, stream>>>(outw, WOUT);   // 4,194,304
  f2b_k<<<1024,  256, 0, stream>>>(W1,   WW1);    //   262,144
  f2b_k<<<16384, 256, 0, stream>>>(W2,   WW2);    // 4,194,304

  embed_k<<<8192, 256, 0, stream>>>(tok, emb, X);

  for (int l = 0; l < 32; ++l) {
    const float*  lnw_l  = lnw  + (size_t)l * 256;
    const float*  lnb_l  = lnb  + (size_t)l * 256;
    const __bf16* inw_l  = WIN  + (size_t)l * 1024 * 256;
    const float*  cw_l   = cw   + (size_t)l * 512 * 4;
    const float*  cb_l   = cb   + (size_t)l * 512;
    const __bf16* xpw_l  = WXP  + (size_t)l * 48 * 512;
    const float*  dtw_l  = dtw  + (size_t)l * 512 * 16;
    const float*  dtb_l  = dtb  + (size_t)l * 512;
    const float*  alog_l = alog + (size_t)l * 512 * 16;
    const float*  dsk_l  = dsk  + (size_t)l * 512;
    const __bf16* outw_l = WOUT + (size_t)l * 256 * 512;

    ln_k<<<8192, 256, 0, stream>>>(X, lnw_l, lnb_l, H);
    gemm_bt<0><<<dim3(8, 64), 256, 0, stream>>>(H, inw_l, XZ, nullptr, nullptr, 8192, 1024, 256);
    conv_silu_k<<<16384, 256, 0, stream>>>(XZ, cw_l, cb_l, XC);
    gemm_bt<4><<<dim3(1, 64), 256, 0, stream>>>(XC, xpw_l, DBC, nullptr, nullptr, 8192, 48, 512);
    scan_pass1<<<dim3(2, 32, 8), 256, 0, stream>>>(DBC, XC, dtw_l, dtb_l, alog_l, PART, PROD);
    scan_combine<<<1024, 256, 0, stream>>>(PART, PROD, H0);
    scan_pass2<<<dim3(2, 32, 8), 256, 0, stream>>>(DBC, XC, XZ, dtw_l, dtb_l, alog_l, dsk_l, H0, Y);
    gemm_bt<3><<<dim3(2, 64), 256, 0, stream>>>(Y, outw_l, X, nullptr, X, 8192, 256, 512);
  }

  f2b_k<<<8192, 256, 0, stream>>>(X, XB);   // f32 residual -> bf16 head input
  gemm_bt<1><<<dim3(8, 64), 256, 0, stream>>>(XB, WW1, HH, b1, nullptr, 8192, 1024, 256);
  gemm_bt<2><<<dim3(32, 64), 256, 0, stream>>>(HH, WW2, (float*)d_out, b2, nullptr, 8192, 4096, 1024);
}

// Round 3
// 4918.246 us; speedup vs baseline: 1.2193x; 1.2193x over previous
//
#include <hip/hip_runtime.h>
#include <hip/hip_bf16.h>
#include <cstdint>
#include <cstddef>

// ---------------------------------------------------------------------------
// Model dims: NL=32, D=256, DI=512, N=16, R=16, K=4, V=4096, FF=1024, B=32, L=256
// All harness inputs/outputs float32. GEMMs run bf16 MFMA; residual/dt/B/C f32.
// R3: dispatch-count attack — 271 -> 165 dispatches via fusion:
//   embed+ln | in_proj gemm | conv+silu+x_proj | scan p1 | scan p2(+combine)
//   | out_proj+resid+ln(next)  (5/layer)
// ---------------------------------------------------------------------------

typedef __bf16 v8bf __attribute__((ext_vector_type(8)));
typedef float  v4f  __attribute__((ext_vector_type(4)));

__device__ __forceinline__ void async_copy16(const void* g, void* l) {
  __builtin_amdgcn_global_load_lds((const __attribute__((address_space(1))) void*)g,
                                   (__attribute__((address_space(3))) void*)l, 16, 0, 0);
}

__device__ __forceinline__ float bf(__bf16 v) { return (float)v; }

// ---------------- workspace layout (bytes) ---------------------------------
constexpr size_t OFF_WIN  = 0;           // bf16 32*1024*256
constexpr size_t OFF_WXP  = 16777216;    // bf16 32*48*512
constexpr size_t OFF_WOUT = 18350080;    // bf16 32*256*512
constexpr size_t OFF_WW1  = 26738688;    // bf16 1024*256
constexpr size_t OFF_WW2  = 27262976;    // bf16 4096*1024
constexpr size_t OFF_X    = 35651584;    // f32  8192*256   residual stream
constexpr size_t OFF_H    = 44040192;    // bf16 8192*256   LN output
constexpr size_t OFF_XZ   = 48234496;    // bf16 8192*1024  in_proj out
constexpr size_t OFF_XC   = 65011712;    // bf16 8192*512   conv+silu out
constexpr size_t OFF_DBC  = 73400320;    // f32  8192*48    x_proj out
constexpr size_t OFF_Y    = 74973184;    // bf16 8192*512   gated ssm out
constexpr size_t OFF_PART = 83361792;    // f32  7*32*512*16 (alias: XB head in)
constexpr size_t OFF_PROD = 91750400;    // f32  same        (alias: HH head mid)
// HH extends to 108,527,616 B (proven available in R2)

// ---------------- batched f32 -> bf16 weight conversion --------------------
__global__ __launch_bounds__(256)
void f2b_multi(const float* __restrict__ s0, const float* __restrict__ s1,
               const float* __restrict__ s2, const float* __restrict__ s3,
               const float* __restrict__ s4, char* __restrict__ ws) {
  size_t i = (size_t)blockIdx.x * 256 + threadIdx.x;
  if (i < 8388608) { ((__bf16*)(ws + OFF_WIN))[i] = (__bf16)s0[i]; return; }
  i -= 8388608;
  if (i < 786432)  { ((__bf16*)(ws + OFF_WXP))[i] = (__bf16)s1[i]; return; }
  i -= 786432;
  if (i < 4194304) { ((__bf16*)(ws + OFF_WOUT))[i] = (__bf16)s2[i]; return; }
  i -= 4194304;
  if (i < 262144)  { ((__bf16*)(ws + OFF_WW1))[i] = (__bf16)s3[i]; return; }
  i -= 262144;
  ((__bf16*)(ws + OFF_WW2))[i] = (__bf16)s4[i];
}

__global__ __launch_bounds__(256) void f2b_k(const float* __restrict__ X,
                                             __bf16* __restrict__ O) {
  size_t i = (size_t)blockIdx.x * 256 + threadIdx.x;
  O[i] = (__bf16)X[i];
}

// ---------------- embed + layer-0 LN ---------------------------------------
__global__ __launch_bounds__(256)
void embed_ln_k(const int* __restrict__ tok, const float* __restrict__ emb,
                const float* __restrict__ w, const float* __restrict__ b,
                float* __restrict__ X, __bf16* __restrict__ H) {
  int row = blockIdx.x;
  int t   = threadIdx.x;
  float v = emb[(size_t)tok[row] * 256 + t];
  X[(size_t)row * 256 + t] = v;
  float s = v, q = v * v;
  #pragma unroll
  for (int o = 32; o > 0; o >>= 1) { s += __shfl_xor(s, o); q += __shfl_xor(q, o); }
  __shared__ float ss[4], qq[4];
  int wv = t >> 6;
  if ((t & 63) == 0) { ss[wv] = s; qq[wv] = q; }
  __syncthreads();
  s = ss[0] + ss[1] + ss[2] + ss[3];
  q = qq[0] + qq[1] + qq[2] + qq[3];
  float mu  = s * (1.f / 256.f);
  float var = q * (1.f / 256.f) - mu * mu;
  float r   = rsqrtf(var + 1e-5f);
  H[(size_t)row * 256 + t] = (__bf16)((v - mu) * r * w[t] + b[t]);
}

// ---------------- generic MFMA bf16 GEMM: C(M,N) = A(M,K) @ W(N,K)^T -------
// BM=BN=128, BK=32, 256 threads. EPI: 0 = bf16; 1 = +bias relu bf16; 2 = +bias f32
template <int EPI>
__global__ __launch_bounds__(256, 2)
void gemm_bt(const __bf16* __restrict__ A, const __bf16* __restrict__ W,
             void* outp, const float* __restrict__ bias, int M, int N, int K) {
  __shared__ __align__(16) __bf16 sA[128 * 32];
  __shared__ __align__(16) __bf16 sB[128 * 32];
  const int tid  = threadIdx.x;
  const int bm0  = blockIdx.y << 7;
  const int bn0  = blockIdx.x << 7;
  const int lane = tid & 63;
  const int wv   = tid >> 6;
  const int wm   = (wv >> 1) << 6;
  const int wn   = (wv & 1) << 6;
  const int lr   = lane & 15;
  const int lk   = lane >> 4;

  v4f acc[4][4] = {};

  const int r0 = tid >> 2;
  const int c0 = (tid & 3) << 3;
  const int wbase = (tid & ~63) << 3;

  const __bf16* gA0 = A + (size_t)(bm0 + r0) * K + c0;
  const __bf16* gA1 = A + (size_t)(bm0 + 64 + r0) * K + c0;
  const __bf16* gB0 = W + (size_t)(bn0 + r0) * K + c0;
  const __bf16* gB1 = W + (size_t)(bn0 + 64 + r0) * K + c0;

  for (int kk = 0; kk < K; kk += 32) {
    async_copy16(gA0 + kk, sA + wbase);
    async_copy16(gA1 + kk, sA + 2048 + wbase);
    async_copy16(gB0 + kk, sB + wbase);
    async_copy16(gB1 + kk, sB + 2048 + wbase);
    __syncthreads();
    v8bf af[4], bfr[4];
    #pragma unroll
    for (int i = 0; i < 4; ++i)
      af[i] = *(const v8bf*)(sA + ((wm + i * 16 + lr) << 5) + (lk << 3));
    #pragma unroll
    for (int j = 0; j < 4; ++j)
      bfr[j] = *(const v8bf*)(sB + ((wn + j * 16 + lr) << 5) + (lk << 3));
    #pragma unroll
    for (int i = 0; i < 4; ++i)
      #pragma unroll
      for (int j = 0; j < 4; ++j)
        acc[i][j] = __builtin_amdgcn_mfma_f32_16x16x32_bf16(af[i], bfr[j], acc[i][j], 0, 0, 0);
    __syncthreads();
  }

  #pragma unroll
  for (int i = 0; i < 4; ++i) {
    #pragma unroll
    for (int j = 0; j < 4; ++j) {
      int gc = bn0 + wn + j * 16 + lr;
      #pragma unroll
      for (int v = 0; v < 4; ++v) {
        int gr = bm0 + wm + i * 16 + (lk << 2) + v;
        float val = acc[i][j][v];
        size_t idx = (size_t)gr * N + gc;
        if (EPI == 0) {
          ((__bf16*)outp)[idx] = (__bf16)val;
        } else if (EPI == 1) {
          val += bias[gc]; val = fmaxf(val, 0.f);
          ((__bf16*)outp)[idx] = (__bf16)val;
        } else {
          ((float*)outp)[idx] = val + bias[gc];
        }
      }
    }
  }
}

// ---------------- fused conv+silu + x_proj GEMM ----------------------------
// Block: 32 rows (bl) x 48 out-cols, 192 threads (3 waves, 16 cols each).
// A-tile (XC slice) computed on the fly from XZ (conv K=4 + SiLU), written
// through to global XC. B = x_proj weights (48 x 512 bf16). Grid: 256 blocks.
__global__ __launch_bounds__(192, 2)
void convxproj_k(const __bf16* __restrict__ XZ, const float* __restrict__ cw,
                 const float* __restrict__ cb, const __bf16* __restrict__ Wxp,
                 __bf16* __restrict__ XC, float* __restrict__ DBC) {
  __shared__ __align__(16) __bf16 sA[32 * 32];
  __shared__ __align__(16) __bf16 sB[48 * 32];
  const int tid  = threadIdx.x;
  const int bl0  = blockIdx.x << 5;
  const int lane = tid & 63, wv = tid >> 6;
  const int lr = lane & 15, lk = lane >> 4;
  v4f acc[2] = {};

  const int ar = tid >> 2;          // A chunk row (tid<128): 0..31
  const int ac = (tid & 3) << 3;    // A chunk col offset: 0,8,16,24
  const int bl = bl0 + ar;
  const int l  = bl & 255;

  for (int kk = 0; kk < 512; kk += 32) {
    // B stage (async): chunk = tid, row tid>>2 (0..47), col (tid&3)*8
    async_copy16(Wxp + (size_t)(tid >> 2) * 512 + ((tid & 3) << 3) + kk,
                 sB + ((tid & ~63) << 3));
    // A stage: conv+silu for e = kk+ac .. +7
    if (tid < 128) {
      const int e = kk + ac;
      float a[8];
      #pragma unroll
      for (int j = 0; j < 8; ++j) a[j] = cb[e + j];
      #pragma unroll
      for (int k = 0; k < 4; ++k) {
        if (l + k >= 3) {
          const v8bf xv = *(const v8bf*)(XZ + (size_t)(bl + k - 3) * 1024 + e);
          #pragma unroll
          for (int j = 0; j < 8; ++j) a[j] += bf(xv[j]) * cw[(e + j) * 4 + k];
        }
      }
      v8bf outv;
      #pragma unroll
      for (int j = 0; j < 8; ++j) {
        float s = a[j] / (1.f + __expf(-a[j]));
        outv[j] = (__bf16)s;
      }
      *(v8bf*)(sA + ar * 32 + ac) = outv;
      *(v8bf*)(XC + (size_t)bl * 512 + e) = outv;
    }
    __syncthreads();
    v8bf af[2], bfr;
    #pragma unroll
    for (int i = 0; i < 2; ++i)
      af[i] = *(const v8bf*)(sA + ((i * 16 + lr) << 5) + (lk << 3));
    bfr = *(const v8bf*)(sB + ((wv * 16 + lr) << 5) + (lk << 3));
    #pragma unroll
    for (int i = 0; i < 2; ++i)
      acc[i] = __builtin_amdgcn_mfma_f32_16x16x32_bf16(af[i], bfr, acc[i], 0, 0, 0);
    __syncthreads();
  }
  const int gc = wv * 16 + lr;   // 0..47, exact
  #pragma unroll
  for (int i = 0; i < 2; ++i)
    #pragma unroll
    for (int v = 0; v < 4; ++v) {
      int gr = bl0 + i * 16 + (lk << 2) + v;
      DBC[(size_t)gr * 48 + gc] = acc[i][v];
    }
}

// ---------------- SSM scan pass1: chunks 0..6 (chunk 7 never consumed) -----
__global__ __launch_bounds__(256, 2)
void scan_pass1(const float* __restrict__ DBC, const __bf16* __restrict__ XC,
                const float* __restrict__ dtw, const float* __restrict__ dtb,
                const float* __restrict__ Alog,
                float* __restrict__ PART, float* __restrict__ PROD) {
  const int e = blockIdx.x * 256 + threadIdx.x;
  const int b = blockIdx.y;
  const int c = blockIdx.z;                       // 0..6
  float Arow[16], Wdt[16];
  #pragma unroll
  for (int n = 0; n < 16; ++n) {
    Arow[n] = -__expf(Alog[e * 16 + n]);
    Wdt[n]  = dtw[e * 16 + n];
  }
  const float bias = dtb[e];
  float part[16], prod[16];
  #pragma unroll
  for (int n = 0; n < 16; ++n) { part[n] = 0.f; prod[n] = 1.f; }
  const int bl0 = b * 256 + c * 32;
  for (int tt = 0; tt < 32; ++tt) {
    const v4f* dp = (const v4f*)(DBC + (size_t)(bl0 + tt) * 48);
    v4f d0 = dp[0], d1 = dp[1], d2 = dp[2], d3 = dp[3];
    v4f bv0 = dp[4], bv1 = dp[5], bv2 = dp[6], bv3 = dp[7];
    float dtv = bias;
    #pragma unroll
    for (int r = 0; r < 4; ++r)
      dtv += d0[r] * Wdt[r] + d1[r] * Wdt[r + 4] + d2[r] * Wdt[r + 8] + d3[r] * Wdt[r + 12];
    dtv = (dtv > 20.f) ? dtv : log1pf(__expf(dtv));
    float x = bf(XC[(size_t)(bl0 + tt) * 512 + e]);
    float dtx = dtv * x;
    float Bv[16];
    #pragma unroll
    for (int r = 0; r < 4; ++r) { Bv[r] = bv0[r]; Bv[r+4] = bv1[r]; Bv[r+8] = bv2[r]; Bv[r+12] = bv3[r]; }
    #pragma unroll
    for (int n = 0; n < 16; ++n) {
      float dA = __expf(dtv * Arow[n]);
      part[n] = part[n] * dA + dtx * Bv[n];
      prod[n] *= dA;
    }
  }
  size_t o = (((size_t)c * 32 + b) * 512 + e) * 16;
  #pragma unroll
  for (int n = 0; n < 16; ++n) { PART[o + n] = part[n]; PROD[o + n] = prod[n]; }
}

// ---------------- SSM scan pass2 + inline chunk combine + gate -------------
__global__ __launch_bounds__(256, 2)
void scan_pass2(const float* __restrict__ DBC, const __bf16* __restrict__ XC,
                const __bf16* __restrict__ XZ,
                const float* __restrict__ dtw, const float* __restrict__ dtb,
                const float* __restrict__ Alog, const float* __restrict__ Dskip,
                const float* __restrict__ PART, const float* __restrict__ PROD,
                __bf16* __restrict__ Y) {
  const int e = blockIdx.x * 256 + threadIdx.x;
  const int b = blockIdx.y;
  const int c = blockIdx.z;                       // 0..7
  float Arow[16], Wdt[16];
  #pragma unroll
  for (int n = 0; n < 16; ++n) {
    Arow[n] = -__expf(Alog[e * 16 + n]);
    Wdt[n]  = dtw[e * 16 + n];
  }
  const float bias = dtb[e];
  const float Dsk  = Dskip[e];
  float h[16];
  #pragma unroll
  for (int n = 0; n < 16; ++n) h[n] = 0.f;
  for (int cc = 0; cc < c; ++cc) {               // chunk-prefix combine
    size_t o = (((size_t)cc * 32 + b) * 512 + e) * 16;
    const v4f* pp = (const v4f*)(PART + o);
    const v4f* qq = (const v4f*)(PROD + o);
    #pragma unroll
    for (int r = 0; r < 4; ++r) {
      v4f p = pp[r], q = qq[r];
      #pragma unroll
      for (int v = 0; v < 4; ++v) h[r * 4 + v] = q[v] * h[r * 4 + v] + p[v];
    }
  }
  const int bl0 = b * 256 + c * 32;
  for (int tt = 0; tt < 32; ++tt) {
    const v4f* dp = (const v4f*)(DBC + (size_t)(bl0 + tt) * 48);
    v4f d0 = dp[0], d1 = dp[1], d2 = dp[2], d3 = dp[3];
    v4f bv0 = dp[4], bv1 = dp[5], bv2 = dp[6], bv3 = dp[7];
    v4f cv0 = dp[8], cv1 = dp[9], cv2 = dp[10], cv3 = dp[11];
    float dtv = bias;
    #pragma unroll
    for (int r = 0; r < 4; ++r)
      dtv += d0[r] * Wdt[r] + d1[r] * Wdt[r + 4] + d2[r] * Wdt[r + 8] + d3[r] * Wdt[r + 12];
    dtv = (dtv > 20.f) ? dtv : log1pf(__expf(dtv));
    float x = bf(XC[(size_t)(bl0 + tt) * 512 + e]);
    float dtx = dtv * x;
    float Bv[16], Cv[16];
    #pragma unroll
    for (int r = 0; r < 4; ++r) {
      Bv[r] = bv0[r]; Bv[r+4] = bv1[r]; Bv[r+8] = bv2[r]; Bv[r+12] = bv3[r];
      Cv[r] = cv0[r]; Cv[r+4] = cv1[r]; Cv[r+8] = cv2[r]; Cv[r+12] = cv3[r];
    }
    float y = 0.f;
    #pragma unroll
    for (int n = 0; n < 16; ++n) {
      float dA = __expf(dtv * Arow[n]);
      h[n] = h[n] * dA + dtx * Bv[n];
      y += h[n] * Cv[n];
    }
    float z  = bf(XZ[(size_t)(bl0 + tt) * 1024 + 512 + e]);
    float sg = z / (1.f + __expf(-z));
    Y[(size_t)(bl0 + tt) * 512 + e] = (__bf16)((y + x * Dsk) * sg);
  }
}

// ---------------- out_proj GEMM + residual + LN(next layer) ----------------
// Block: 32 rows x 256 cols (full D), 256 threads (4 waves, 64 cols each).
// X (f32 residual) updated in place; H = LN(X_new) with next layer's weights.
__global__ __launch_bounds__(256, 2)
void gemm_out_ln_k(const __bf16* __restrict__ Yb, const __bf16* __restrict__ Wout,
                   const float* __restrict__ lnw, const float* __restrict__ lnb,
                   float* __restrict__ X, __bf16* __restrict__ H) {
  __shared__ __align__(16) __bf16 sA[32 * 32];
  __shared__ __align__(16) __bf16 sB[256 * 32];
  __shared__ float sSum[4][32], sSq[4][32];
  const int tid  = threadIdx.x;
  const int bm0  = blockIdx.x << 5;
  const int lane = tid & 63, wv = tid >> 6;
  const int lr = lane & 15, lk = lane >> 4;
  v4f acc[2][4] = {};

  const int ar = tid >> 2;          // A chunk (tid<128)
  const int ac = (tid & 3) << 3;

  for (int kk = 0; kk < 512; kk += 32) {
    if (tid < 128)
      async_copy16(Yb + (size_t)(bm0 + ar) * 512 + ac + kk, sA + ((tid & ~63) << 3));
    #pragma unroll
    for (int j = 0; j < 4; ++j) {
      int ch = j * 256 + tid;
      async_copy16(Wout + (size_t)(ch >> 2) * 512 + ((ch & 3) << 3) + kk,
                   sB + ((j * 256 + (tid & ~63)) << 3));
    }
    __syncthreads();
    v8bf af[2], bfr[4];
    #pragma unroll
    for (int i = 0; i < 2; ++i)
      af[i] = *(const v8bf*)(sA + ((i * 16 + lr) << 5) + (lk << 3));
    #pragma unroll
    for (int j = 0; j < 4; ++j)
      bfr[j] = *(const v8bf*)(sB + ((wv * 64 + j * 16 + lr) << 5) + (lk << 3));
    #pragma unroll
    for (int i = 0; i < 2; ++i)
      #pragma unroll
      for (int j = 0; j < 4; ++j)
        acc[i][j] = __builtin_amdgcn_mfma_f32_16x16x32_bf16(af[i], bfr[j], acc[i][j], 0, 0, 0);
    __syncthreads();
  }

  // residual add (in-register) + per-row sums
  float s2[2][4], q2[2][4];
  #pragma unroll
  for (int i = 0; i < 2; ++i)
    #pragma unroll
    for (int v = 0; v < 4; ++v) {
      int gr = bm0 + i * 16 + (lk << 2) + v;
      float s = 0.f, q = 0.f;
      #pragma unroll
      for (int j = 0; j < 4; ++j) {
        int gc = wv * 64 + j * 16 + lr;
        float val = X[(size_t)gr * 256 + gc] + acc[i][j][v];
        acc[i][j][v] = val;
        s += val; q += val * val;
      }
      #pragma unroll
      for (int o = 8; o > 0; o >>= 1) { s += __shfl_xor(s, o); q += __shfl_xor(q, o); }
      s2[i][v] = s; q2[i][v] = q;
    }
  if (lr == 0) {
    #pragma unroll
    for (int i = 0; i < 2; ++i)
      #pragma unroll
      for (int v = 0; v < 4; ++v) {
        int row = i * 16 + (lk << 2) + v;
        sSum[wv][row] = s2[i][v];
        sSq[wv][row]  = q2[i][v];
      }
  }
  __syncthreads();
  #pragma unroll
  for (int i = 0; i < 2; ++i)
    #pragma unroll
    for (int v = 0; v < 4; ++v) {
      int row = i * 16 + (lk << 2) + v;
      float S = sSum[0][row] + sSum[1][row] + sSum[2][row] + sSum[3][row];
      float Q = sSq[0][row]  + sSq[1][row]  + sSq[2][row]  + sSq[3][row];
      float mu  = S * (1.f / 256.f);
      float var = Q * (1.f / 256.f) - mu * mu;
      float rinv = rsqrtf(var + 1e-5f);
      int gr = bm0 + row;
      #pragma unroll
      for (int j = 0; j < 4; ++j) {
        int gc = wv * 64 + j * 16 + lr;
        float val = acc[i][j][v];
        X[(size_t)gr * 256 + gc] = val;
        H[(size_t)gr * 256 + gc] = (__bf16)((val - mu) * rinv * lnw[gc] + lnb[gc]);
      }
    }
}

extern "C" void kernel_launch(void* const* d_in, const int* in_sizes, int n_in,
                              void* d_out, int out_size, void* d_ws, size_t ws_size,
                              hipStream_t stream) {
  const int*   tok  = (const int*)d_in[0];
  const float* emb  = (const float*)d_in[1];
  const float* lnw  = (const float*)d_in[2];
  const float* lnb  = (const float*)d_in[3];
  const float* inw  = (const float*)d_in[4];
  const float* cw   = (const float*)d_in[5];
  const float* cb   = (const float*)d_in[6];
  const float* xpw  = (const float*)d_in[7];
  const float* dtw  = (const float*)d_in[8];
  const float* dtb  = (const float*)d_in[9];
  const float* alog = (const float*)d_in[10];
  const float* dsk  = (const float*)d_in[11];
  const float* outw = (const float*)d_in[12];
  const float* W1   = (const float*)d_in[13];
  const float* b1   = (const float*)d_in[14];
  const float* W2   = (const float*)d_in[15];
  const float* b2   = (const float*)d_in[16];

  char* ws = (char*)d_ws;
  __bf16* WIN  = (__bf16*)(ws + OFF_WIN);
  __bf16* WXP  = (__bf16*)(ws + OFF_WXP);
  __bf16* WOUT = (__bf16*)(ws + OFF_WOUT);
  __bf16* WW1  = (__bf16*)(ws + OFF_WW1);
  __bf16* WW2  = (__bf16*)(ws + OFF_WW2);
  float*  X    = (float*)(ws + OFF_X);
  __bf16* H    = (__bf16*)(ws + OFF_H);
  __bf16* XZ   = (__bf16*)(ws + OFF_XZ);
  __bf16* XC   = (__bf16*)(ws + OFF_XC);
  float*  DBC  = (float*)(ws + OFF_DBC);
  __bf16* Y    = (__bf16*)(ws + OFF_Y);
  float*  PART = (float*)(ws + OFF_PART);
  float*  PROD = (float*)(ws + OFF_PROD);
  __bf16* XB   = (__bf16*)(ws + OFF_PART);   // head-phase aliases
  __bf16* HH   = (__bf16*)(ws + OFF_PROD);

  f2b_multi<<<69632, 256, 0, stream>>>(inw, xpw, outw, W1, W2, ws);
  embed_ln_k<<<8192, 256, 0, stream>>>(tok, emb, lnw, lnb, X, H);

  for (int l = 0; l < 32; ++l) {
    const __bf16* inw_l  = WIN  + (size_t)l * 1024 * 256;
    const float*  cw_l   = cw   + (size_t)l * 512 * 4;
    const float*  cb_l   = cb   + (size_t)l * 512;
    const __bf16* xpw_l  = WXP  + (size_t)l * 48 * 512;
    const float*  dtw_l  = dtw  + (size_t)l * 512 * 16;
    const float*  dtb_l  = dtb  + (size_t)l * 512;
    const float*  alog_l = alog + (size_t)l * 512 * 16;
    const float*  dsk_l  = dsk  + (size_t)l * 512;
    const __bf16* outw_l = WOUT + (size_t)l * 256 * 512;
    const int lnx = (l + 1 < 32) ? l + 1 : 31;   // next layer's LN (unused for l=31)

    gemm_bt<0><<<dim3(8, 64), 256, 0, stream>>>(H, inw_l, XZ, nullptr, 8192, 1024, 256);
    convxproj_k<<<256, 192, 0, stream>>>(XZ, cw_l, cb_l, xpw_l, XC, DBC);
    scan_pass1<<<dim3(2, 32, 7), 256, 0, stream>>>(DBC, XC, dtw_l, dtb_l, alog_l, PART, PROD);
    scan_pass2<<<dim3(2, 32, 8), 256, 0, stream>>>(DBC, XC, XZ, dtw_l, dtb_l, alog_l, dsk_l,
                                                   PART, PROD, Y);
    gemm_out_ln_k<<<256, 256, 0, stream>>>(Y, outw_l, lnw + (size_t)lnx * 256,
                                           lnb + (size_t)lnx * 256, X, H);
  }

  f2b_k<<<8192, 256, 0, stream>>>(X, XB);
  gemm_bt<1><<<dim3(8, 64), 256, 0, stream>>>(XB, WW1, HH, b1, 8192, 1024, 256);
  gemm_bt<2><<<dim3(32, 64), 256, 0, stream>>>(HH, WW2, (float*)d_out, b2, 8192, 4096, 1024);
}